// Round 13
// baseline (469.597 us; speedup 1.0000x reference)
//
#include <hip/hip_runtime.h>
#include <math.h>

#define NN 50000
#define EE 800000
#define HH 64
#define GG 512
#define SCAN_NB ((NN + 1023) / 1024)       // 49 blocks (covers NN+1 entries)
#define FW_NWG 32                          // partitioned-build blocks (dst-range owners)
#define FW_CHUNK ((NN + FW_NWG - 1) / FW_NWG)   // 1563 nodes per owner block

typedef unsigned short ushort_t;
typedef unsigned int uint_t;

__device__ __forceinline__ ushort_t f32_to_bf16(float f) {
    uint_t u = __float_as_uint(f);
    uint_t bias = 0x7FFFu + ((u >> 16) & 1u);    // round-to-nearest-even
    return (ushort_t)((u + bias) >> 16);
}
__device__ __forceinline__ float bf16_to_f32(ushort_t h) {
    return __uint_as_float(((uint_t)h) << 16);
}

// ---------------- partitioned degree count: block owns dst-range, LDS counters ----------------
// No global atomics; deg lines have a single writer block.

__global__ void __launch_bounds__(1024) k_count(const int* __restrict__ dst,
                                                int* __restrict__ deg) {
    __shared__ int cnt[FW_CHUNK];
    int tid = threadIdx.x;
    int lo = blockIdx.x * FW_CHUNK;
    int hi = min(lo + FW_CHUNK, NN);
    for (int j = tid; j < FW_CHUNK; j += 1024) cnt[j] = 0;
    __syncthreads();
    for (int e0 = tid * 8; e0 < EE; e0 += 8192) {      // 2 independent int4 loads/iter
        int4 a = *(const int4*)(dst + e0);
        int4 b = *(const int4*)(dst + e0 + 4);
        if (a.x >= lo && a.x < hi) atomicAdd(&cnt[a.x - lo], 1);
        if (a.y >= lo && a.y < hi) atomicAdd(&cnt[a.y - lo], 1);
        if (a.z >= lo && a.z < hi) atomicAdd(&cnt[a.z - lo], 1);
        if (a.w >= lo && a.w < hi) atomicAdd(&cnt[a.w - lo], 1);
        if (b.x >= lo && b.x < hi) atomicAdd(&cnt[b.x - lo], 1);
        if (b.y >= lo && b.y < hi) atomicAdd(&cnt[b.y - lo], 1);
        if (b.z >= lo && b.z < hi) atomicAdd(&cnt[b.z - lo], 1);
        if (b.w >= lo && b.w < hi) atomicAdd(&cnt[b.w - lo], 1);
    }
    __syncthreads();
    for (int j = tid; lo + j < hi; j += 1024) deg[lo + j] = cnt[j];
}

// ---------------- scan: deg -> block-local rowptr + block sums (+ dinv) ----------------

__global__ void __launch_bounds__(1024) k_scan1(const int* __restrict__ deg,
                                                int* __restrict__ rowptr,
                                                int* __restrict__ bsum,
                                                float* __restrict__ dinv) {
    int tid = threadIdx.x;
    int lane = tid & 63, w = tid >> 6;
    int i = blockIdx.x * 1024 + tid;
    int v = (i < NN) ? deg[i] : 0;
    if (i < NN)       dinv[i] = 1.0f / sqrtf((float)(v + 1));   // +1 self-loop
    else if (i == NN) dinv[i] = 0.0f;                           // zero row
    int x = v;                                                  // inclusive wave scan
#pragma unroll
    for (int off = 1; off < 64; off <<= 1) {
        int y = __shfl_up(x, off);
        if (lane >= off) x += y;
    }
    __shared__ int ws[16];
    if (lane == 63) ws[w] = x;
    __syncthreads();
    if (tid < 16) {
        int y = ws[tid];
        int z = y;
#pragma unroll
        for (int off = 1; off < 16; off <<= 1) {
            int t2 = __shfl_up(z, off);
            if (tid >= off) z += t2;
        }
        ws[tid] = z - y;                          // exclusive wave offsets
    }
    __syncthreads();
    int excl = x - v + ws[w];
    if (i <= NN) rowptr[i] = excl;                // block-local exclusive prefix
    if (tid == 1023) bsum[blockIdx.x] = excl + v; // block total
}

__global__ void __launch_bounds__(64) k_scan2(int* __restrict__ bsum) {
    int lane = threadIdx.x;
    int v = (lane < SCAN_NB) ? bsum[lane] : 0;
    int x = v;
#pragma unroll
    for (int off = 1; off < 64; off <<= 1) {
        int y = __shfl_up(x, off);
        if (lane >= off) x += y;
    }
    if (lane < SCAN_NB) bsum[lane] = x - v;       // exclusive block offsets
}

// ---------------- partitioned CSR fill: LDS cursors + preloaded row bases ----------------
// Single writer block per csr_src line -> no cross-XCD write amplification.

__global__ void __launch_bounds__(1024) k_fillp(const int* __restrict__ src,
                                                const int* __restrict__ dst,
                                                const int* __restrict__ rowptr,
                                                const int* __restrict__ bsum,
                                                int* __restrict__ csr_src) {
    __shared__ int cur[FW_CHUNK];
    __shared__ int base[FW_CHUNK];
    int tid = threadIdx.x;
    int lo = blockIdx.x * FW_CHUNK;
    int hi = min(lo + FW_CHUNK, NN);
    for (int j = tid; j < FW_CHUNK; j += 1024) {
        cur[j] = 0;
        int i = lo + j;
        base[j] = (i < NN) ? rowptr[i] + bsum[i >> 10] : 0;
    }
    __syncthreads();
    for (int e0 = tid * 8; e0 < EE; e0 += 8192) {
        int4 da = *(const int4*)(dst + e0);
        int4 db = *(const int4*)(dst + e0 + 4);
        int4 sa = *(const int4*)(src + e0);
        int4 sb = *(const int4*)(src + e0 + 4);
        if (da.x >= lo && da.x < hi) { int p = atomicAdd(&cur[da.x - lo], 1); csr_src[base[da.x - lo] + p] = sa.x; }
        if (da.y >= lo && da.y < hi) { int p = atomicAdd(&cur[da.y - lo], 1); csr_src[base[da.y - lo] + p] = sa.y; }
        if (da.z >= lo && da.z < hi) { int p = atomicAdd(&cur[da.z - lo], 1); csr_src[base[da.z - lo] + p] = sa.z; }
        if (da.w >= lo && da.w < hi) { int p = atomicAdd(&cur[da.w - lo], 1); csr_src[base[da.w - lo] + p] = sa.w; }
        if (db.x >= lo && db.x < hi) { int p = atomicAdd(&cur[db.x - lo], 1); csr_src[base[db.x - lo] + p] = sb.x; }
        if (db.y >= lo && db.y < hi) { int p = atomicAdd(&cur[db.y - lo], 1); csr_src[base[db.y - lo] + p] = sb.y; }
        if (db.z >= lo && db.z < hi) { int p = atomicAdd(&cur[db.z - lo], 1); csr_src[base[db.z - lo] + p] = sb.z; }
        if (db.w >= lo && db.w < hi) { int p = atomicAdd(&cur[db.w - lo], 1); csr_src[base[db.w - lo] + p] = sb.w; }
    }
}

// ---------------- per-graph node counts ----------------

__global__ void k_cnt(const int* __restrict__ batch, int* __restrict__ cnt) {
    int i = blockIdx.x * blockDim.x + threadIdx.x;
    if (i < NN) atomicAdd(&cnt[batch[i]], 1);
}

// ---------------- dense transform: t' = bf16((act(x) @ W) * dinv[row]); row NN zeroed ------

template<bool RELU>
__global__ void __launch_bounds__(256) k_xform(const float* __restrict__ x,
                                               const float* __restrict__ W,
                                               const float* __restrict__ dinv,
                                               ushort_t* __restrict__ t) {
    __shared__ float sW[64 * 64];   // 16 KB
    __shared__ float sX[32 * 65];   // padded
    int tid = threadIdx.x;
    for (int k = tid; k < 64 * 64; k += 256) sW[k] = W[k];
    int row0 = blockIdx.x * 32;
    for (int v = tid; v < 32 * 16; v += 256) {
        int r  = v >> 4;
        int k4 = (v & 15) * 4;
        int row = row0 + r;
        float4 val = make_float4(0.f, 0.f, 0.f, 0.f);
        if (row < NN) val = *(const float4*)(x + (size_t)row * 64 + k4);
        if (RELU) {
            val.x = fmaxf(val.x, 0.f); val.y = fmaxf(val.y, 0.f);
            val.z = fmaxf(val.z, 0.f); val.w = fmaxf(val.w, 0.f);
        }
        sX[r * 65 + k4 + 0] = val.x;
        sX[r * 65 + k4 + 1] = val.y;
        sX[r * 65 + k4 + 2] = val.z;
        sX[r * 65 + k4 + 3] = val.w;
    }
    __syncthreads();
    int r  = tid >> 3;        // 0..31
    int c0 = (tid & 7) * 8;   // 0,8,...,56
    float acc[8] = {0.f, 0.f, 0.f, 0.f, 0.f, 0.f, 0.f, 0.f};
    for (int k = 0; k < 64; ++k) {
        float xv = sX[r * 65 + k];
#pragma unroll
        for (int j = 0; j < 8; ++j) acc[j] = fmaf(xv, sW[k * 64 + c0 + j], acc[j]);
    }
    int row = row0 + r;
    if (row <= NN) {          // row NN: acc==0 -> writes zero row
        float dv = dinv[row];
        uint_t pk[4];
#pragma unroll
        for (int j = 0; j < 4; ++j) {
            ushort_t lol = f32_to_bf16(acc[2 * j] * dv);
            ushort_t hih = f32_to_bf16(acc[2 * j + 1] * dv);
            pk[j] = (uint_t)lol | ((uint_t)hih << 16);
        }
        uint4* o = (uint4*)(t + (size_t)row * 64 + c0);   // 16 B per lane
        *o = make_uint4(pk[0], pk[1], pk[2], pk[3]);
    }
}

// ---------------- CSR gather: one wave per node, 16-deep batches, bf16 rows ----------------
// out[i] = dinv[i] * (t'[i] + sum_{s in N(i)} t'[s]) + b

template<bool POOL>
__global__ void __launch_bounds__(256) k_gather(const ushort_t* __restrict__ t,
                                                const float* __restrict__ dinv,
                                                const int* __restrict__ rowptr,
                                                const int* __restrict__ bsum,
                                                const int* __restrict__ csr_src,
                                                const float* __restrict__ b,
                                                const int* __restrict__ batch,
                                                float* __restrict__ out) {
    int i = __builtin_amdgcn_readfirstlane((blockIdx.x * blockDim.x + threadIdx.x) >> 6);
    int c = threadIdx.x & 63;
    if (i >= NN) return;
    int e   = __builtin_amdgcn_readfirstlane(rowptr[i]     + bsum[i >> 10]);
    int end = __builtin_amdgcn_readfirstlane(rowptr[i + 1] + bsum[(i + 1) >> 10]);
    float acc = bf16_to_f32(t[(size_t)i * 64 + c]);   // self-loop (t' already *dinv[i])
    float a0 = 0.f, a1 = 0.f, a2 = 0.f, a3 = 0.f;
    for (; e < end; e += 16) {                    // 16 outstanding row-gathers
        int s[16];
#pragma unroll
        for (int j = 0; j < 16; ++j) {
            int sj = csr_src[e + j];              // uniform addr -> scalar load
            s[j] = (e + j < end) ? sj : NN;       // uniform select; NN = zero row
        }
        ushort_t v[16];
#pragma unroll
        for (int j = 0; j < 16; ++j) v[j] = t[(size_t)s[j] * 64 + c];
#pragma unroll
        for (int j = 0; j < 16; ++j) {
            float f = bf16_to_f32(v[j]);
            if ((j & 3) == 0)      a0 += f;
            else if ((j & 3) == 1) a1 += f;
            else if ((j & 3) == 2) a2 += f;
            else                   a3 += f;
        }
    }
    acc += (a0 + a1) + (a2 + a3);
    float r = fmaf(acc, dinv[i], b[c]);
    if (POOL) {
        atomicAdd(&out[(size_t)batch[i] * 64 + c], fmaxf(r, 0.0f));
    } else {
        out[(size_t)i * 64 + c] = r;
    }
}

// ---------------- head: per-graph MLP, one wave per graph ----------------

__global__ void __launch_bounds__(64) k_head(const float* __restrict__ pooled,
                                             const int* __restrict__ cnt,
                                             const float* __restrict__ w1,
                                             const float* __restrict__ b1,
                                             const float* __restrict__ w2,
                                             const float* __restrict__ b2,
                                             float* __restrict__ out) {
    int g = blockIdx.x;
    int c = threadIdx.x;
    __shared__ float sp[64];
    float cf = fmaxf((float)cnt[g], 1.0f);
    sp[c] = pooled[(size_t)g * 64 + c] / cf;
    __syncthreads();
    float acc = b1[c];
    for (int k = 0; k < 64; ++k) acc = fmaf(sp[k], w1[k * 64 + c], acc);
    float h1 = fmaxf(acc, 0.0f);
    float p = h1 * w2[c];
#pragma unroll
    for (int off = 32; off > 0; off >>= 1) p += __shfl_down(p, off);
    if (c == 0) out[g] = p + b2[0];
}

// ---------------- launch ----------------

extern "C" void kernel_launch(void* const* d_in, const int* in_sizes, int n_in,
                              void* d_out, int out_size, void* d_ws, size_t ws_size,
                              hipStream_t stream) {
    const float* x      = (const float*)d_in[0];
    const int*   ei     = (const int*)d_in[1];
    const int*   batch  = (const int*)d_in[2];
    const float* W0     = (const float*)d_in[3];
    const float* b0     = (const float*)d_in[4];
    const float* W1     = (const float*)d_in[5];
    const float* b1     = (const float*)d_in[6];
    const float* W2     = (const float*)d_in[7];
    const float* b2     = (const float*)d_in[8];
    const float* lin1w  = (const float*)d_in[9];
    const float* lin1b  = (const float*)d_in[10];
    const float* lin2w  = (const float*)d_in[11];
    const float* lin2b  = (const float*)d_in[12];
    float* out = (float*)d_out;

    const int* src = ei;
    const int* dst = ei + EE;

    char* ws = (char*)d_ws;
    size_t off = 0;
    auto carve = [&](size_t bytes) {
        void* p = ws + off;
        off = (off + bytes + 255) & ~(size_t)255;
        return p;
    };
    // zero-initialized group first (single memset covers [0, zero_span))
    float*    pooled   = (float*)carve((size_t)GG * 64 * 4);
    int*      cnt      = (int*)carve((size_t)GG * 4);
    size_t zero_span = off;
    int*      deg      = (int*)carve((size_t)NN * 4);            // fully written by k_count
    float*    dinv     = (float*)carve((size_t)(NN + 1) * 4);
    int*      rowptr   = (int*)carve((size_t)(NN + 1) * 4);
    int*      bsum     = (int*)carve((size_t)SCAN_NB * 4);
    int*      csr_src  = (int*)carve((size_t)(EE + 16) * 4);     // +16 for masked overrun reads
    ushort_t* bufT     = (ushort_t*)carve((size_t)(NN + 1) * 64 * 2);  // bf16, +1 zero row
    float*    bufA     = (float*)carve((size_t)NN * 64 * 4);

    hipMemsetAsync(pooled, 0, zero_span, stream);

    // ---- CSR build (partitioned owner-computes; no global atomics on build path) ----
    k_count<<<FW_NWG, 1024, 0, stream>>>(dst, deg);
    k_scan1<<<SCAN_NB, 1024, 0, stream>>>(deg, rowptr, bsum, dinv);
    k_scan2<<<1, 64, 0, stream>>>(bsum);
    k_fillp<<<FW_NWG, 1024, 0, stream>>>(src, dst, rowptr, bsum, csr_src);
    k_cnt  <<<(NN + 255) / 256, 256, 0, stream>>>(batch, cnt);

    const int xgrid = (NN + 1 + 31) / 32;        // includes zero row NN
    const int ggrid = (NN * 64) / 256;           // one 64-lane wave per node

    // layer 0: x -> bufA
    k_xform<false><<<xgrid, 256, 0, stream>>>(x, W0, dinv, bufT);
    k_gather<false><<<ggrid, 256, 0, stream>>>(bufT, dinv, rowptr, bsum, csr_src,
                                               b0, batch, bufA);
    // layer 1
    k_xform<true><<<xgrid, 256, 0, stream>>>(bufA, W1, dinv, bufT);
    k_gather<false><<<ggrid, 256, 0, stream>>>(bufT, dinv, rowptr, bsum, csr_src,
                                               b1, batch, bufA);
    // layer 2: relu + mean-pool fused into gather
    k_xform<true><<<xgrid, 256, 0, stream>>>(bufA, W2, dinv, bufT);
    k_gather<true><<<ggrid, 256, 0, stream>>>(bufT, dinv, rowptr, bsum, csr_src,
                                              b2, batch, pooled);

    k_head<<<GG, 64, 0, stream>>>(pooled, cnt, lin1w, lin1b, lin2w, lin2b, out);
}

// Round 15
// 324.064 us; speedup vs baseline: 1.4491x; 1.4491x over previous
//
#include <hip/hip_runtime.h>
#include <math.h>

#define NN 50000
#define EE 800000
#define HH 64
#define GG 512
#define SCAN_NB ((NN + 1023) / 1024)       // 49 blocks (covers NN+1 entries)

typedef unsigned short ushort_t;
typedef unsigned int uint_t;

__device__ __forceinline__ ushort_t f32_to_bf16(float f) {
    uint_t u = __float_as_uint(f);
    uint_t bias = 0x7FFFu + ((u >> 16) & 1u);    // round-to-nearest-even
    return (ushort_t)((u + bias) >> 16);
}
__device__ __forceinline__ float bf16_to_f32(ushort_t h) {
    return __uint_as_float(((uint_t)h) << 16);
}

// ---------------- degree + per-edge rank (old value of the atomic) + per-graph counts ------

__global__ void k_deg(const int* __restrict__ dst, const int* __restrict__ batch,
                      int* __restrict__ deg, ushort_t* __restrict__ rank,
                      int* __restrict__ cnt) {
    int tid = blockIdx.x * blockDim.x + threadIdx.x;
    if (tid < EE) {
        rank[tid] = (ushort_t)atomicAdd(&deg[dst[tid]], 1);
    } else if (tid < EE + NN) {
        atomicAdd(&cnt[batch[tid - EE]], 1);
    }
}

// ---------------- scan: deg -> block-local rowptr + block sums (+ dinv) ----------------

__global__ void __launch_bounds__(1024) k_scan1(const int* __restrict__ deg,
                                                int* __restrict__ rowptr,
                                                int* __restrict__ bsum,
                                                float* __restrict__ dinv) {
    int tid = threadIdx.x;
    int lane = tid & 63, w = tid >> 6;
    int i = blockIdx.x * 1024 + tid;
    int v = (i < NN) ? deg[i] : 0;
    if (i < NN)       dinv[i] = 1.0f / sqrtf((float)(v + 1));   // +1 self-loop
    else if (i == NN) dinv[i] = 0.0f;                           // zero row
    int x = v;                                                  // inclusive wave scan
#pragma unroll
    for (int off = 1; off < 64; off <<= 1) {
        int y = __shfl_up(x, off);
        if (lane >= off) x += y;
    }
    __shared__ int ws[16];
    if (lane == 63) ws[w] = x;
    __syncthreads();
    if (tid < 16) {
        int y = ws[tid];
        int z = y;
#pragma unroll
        for (int off = 1; off < 16; off <<= 1) {
            int t2 = __shfl_up(z, off);
            if (tid >= off) z += t2;
        }
        ws[tid] = z - y;                          // exclusive wave offsets
    }
    __syncthreads();
    int excl = x - v + ws[w];
    if (i <= NN) rowptr[i] = excl;                // block-local exclusive prefix
    if (tid == 1023) bsum[blockIdx.x] = excl + v; // block total
}

__global__ void __launch_bounds__(64) k_scan2(int* __restrict__ bsum) {
    int lane = threadIdx.x;
    int v = (lane < SCAN_NB) ? bsum[lane] : 0;
    int x = v;
#pragma unroll
    for (int off = 1; off < 64; off <<= 1) {
        int y = __shfl_up(x, off);
        if (lane >= off) x += y;
    }
    if (lane < SCAN_NB) bsum[lane] = x - v;       // exclusive block offsets
}

// ---------------- CSR fill: atomic-free u16 edge scatter ----------------

__global__ void k_fill(const int* __restrict__ src, const int* __restrict__ dst,
                       const ushort_t* __restrict__ rank,
                       const int* __restrict__ rowptr, const int* __restrict__ bsum,
                       ushort_t* __restrict__ csr_src) {
    int tid = blockIdx.x * blockDim.x + threadIdx.x;
    if (tid >= EE) return;
    int d = dst[tid];
    csr_src[rowptr[d] + bsum[d >> 10] + (int)rank[tid]] = (ushort_t)src[tid];
}

// ---------------- dense transform: t' = bf16((act(x) @ W) * dinv[row]); row NN zeroed ------

template<bool RELU>
__global__ void __launch_bounds__(256) k_xform(const float* __restrict__ x,
                                               const float* __restrict__ W,
                                               const float* __restrict__ dinv,
                                               ushort_t* __restrict__ t) {
    __shared__ float sW[64 * 64];   // 16 KB
    __shared__ float sX[32 * 65];   // padded
    int tid = threadIdx.x;
    for (int k = tid; k < 64 * 64; k += 256) sW[k] = W[k];
    int row0 = blockIdx.x * 32;
    for (int v = tid; v < 32 * 16; v += 256) {
        int r  = v >> 4;
        int k4 = (v & 15) * 4;
        int row = row0 + r;
        float4 val = make_float4(0.f, 0.f, 0.f, 0.f);
        if (row < NN) val = *(const float4*)(x + (size_t)row * 64 + k4);
        if (RELU) {
            val.x = fmaxf(val.x, 0.f); val.y = fmaxf(val.y, 0.f);
            val.z = fmaxf(val.z, 0.f); val.w = fmaxf(val.w, 0.f);
        }
        sX[r * 65 + k4 + 0] = val.x;
        sX[r * 65 + k4 + 1] = val.y;
        sX[r * 65 + k4 + 2] = val.z;
        sX[r * 65 + k4 + 3] = val.w;
    }
    __syncthreads();
    int r  = tid >> 3;        // 0..31
    int c0 = (tid & 7) * 8;   // 0,8,...,56
    float acc[8] = {0.f, 0.f, 0.f, 0.f, 0.f, 0.f, 0.f, 0.f};
    for (int k = 0; k < 64; ++k) {
        float xv = sX[r * 65 + k];
#pragma unroll
        for (int j = 0; j < 8; ++j) acc[j] = fmaf(xv, sW[k * 64 + c0 + j], acc[j]);
    }
    int row = row0 + r;
    if (row <= NN) {          // row NN: acc==0 -> writes zero row
        float dv = dinv[row];
        uint_t pk[4];
#pragma unroll
        for (int j = 0; j < 4; ++j) {
            ushort_t lo = f32_to_bf16(acc[2 * j] * dv);
            ushort_t hi = f32_to_bf16(acc[2 * j + 1] * dv);
            pk[j] = (uint_t)lo | ((uint_t)hi << 16);
        }
        uint4* o = (uint4*)(t + (size_t)row * 64 + c0);   // 16 B per lane
        *o = make_uint4(pk[0], pk[1], pk[2], pk[3]);
    }
}

// ---------------- CSR gather: one wave per node, 16-deep batches, bf16 rows, u16 idx -------
// out[i] = dinv[i] * (t'[i] + sum_{s in N(i)} t'[s]) + b

template<bool POOL>
__global__ void __launch_bounds__(256) k_gather(const ushort_t* __restrict__ t,
                                                const float* __restrict__ dinv,
                                                const int* __restrict__ rowptr,
                                                const int* __restrict__ bsum,
                                                const ushort_t* __restrict__ csr_src,
                                                const float* __restrict__ b,
                                                const int* __restrict__ batch,
                                                float* __restrict__ out) {
    int i = __builtin_amdgcn_readfirstlane((blockIdx.x * blockDim.x + threadIdx.x) >> 6);
    int c = threadIdx.x & 63;
    if (i >= NN) return;
    int e   = __builtin_amdgcn_readfirstlane(rowptr[i]     + bsum[i >> 10]);
    int end = __builtin_amdgcn_readfirstlane(rowptr[i + 1] + bsum[(i + 1) >> 10]);
    float acc = bf16_to_f32(t[(size_t)i * 64 + c]);   // self-loop (t' already *dinv[i])
    float a0 = 0.f, a1 = 0.f, a2 = 0.f, a3 = 0.f;
    for (; e < end; e += 16) {                    // 16 outstanding row-gathers
        int s[16];
#pragma unroll
        for (int j = 0; j < 16; ++j) {
            int sj = (int)csr_src[e + j];         // uniform addr -> one line, broadcast
            s[j] = (e + j < end) ? sj : NN;       // uniform select; NN = zero row
        }
        ushort_t v[16];
#pragma unroll
        for (int j = 0; j < 16; ++j) v[j] = t[(size_t)s[j] * 64 + c];
#pragma unroll
        for (int j = 0; j < 16; ++j) {
            float f = bf16_to_f32(v[j]);
            if ((j & 3) == 0)      a0 += f;
            else if ((j & 3) == 1) a1 += f;
            else if ((j & 3) == 2) a2 += f;
            else                   a3 += f;
        }
    }
    acc += (a0 + a1) + (a2 + a3);
    float r = fmaf(acc, dinv[i], b[c]);
    if (POOL) {
        atomicAdd(&out[(size_t)batch[i] * 64 + c], fmaxf(r, 0.0f));
    } else {
        out[(size_t)i * 64 + c] = r;
    }
}

// ---------------- head: per-graph MLP, one wave per graph ----------------

__global__ void __launch_bounds__(64) k_head(const float* __restrict__ pooled,
                                             const int* __restrict__ cnt,
                                             const float* __restrict__ w1,
                                             const float* __restrict__ b1,
                                             const float* __restrict__ w2,
                                             const float* __restrict__ b2,
                                             float* __restrict__ out) {
    int g = blockIdx.x;
    int c = threadIdx.x;
    __shared__ float sp[64];
    float cf = fmaxf((float)cnt[g], 1.0f);
    sp[c] = pooled[(size_t)g * 64 + c] / cf;
    __syncthreads();
    float acc = b1[c];
    for (int k = 0; k < 64; ++k) acc = fmaf(sp[k], w1[k * 64 + c], acc);
    float h1 = fmaxf(acc, 0.0f);
    float p = h1 * w2[c];
#pragma unroll
    for (int off = 32; off > 0; off >>= 1) p += __shfl_down(p, off);
    if (c == 0) out[g] = p + b2[0];
}

// ---------------- launch ----------------

extern "C" void kernel_launch(void* const* d_in, const int* in_sizes, int n_in,
                              void* d_out, int out_size, void* d_ws, size_t ws_size,
                              hipStream_t stream) {
    const float* x      = (const float*)d_in[0];
    const int*   ei     = (const int*)d_in[1];
    const int*   batch  = (const int*)d_in[2];
    const float* W0     = (const float*)d_in[3];
    const float* b0     = (const float*)d_in[4];
    const float* W1     = (const float*)d_in[5];
    const float* b1     = (const float*)d_in[6];
    const float* W2     = (const float*)d_in[7];
    const float* b2     = (const float*)d_in[8];
    const float* lin1w  = (const float*)d_in[9];
    const float* lin1b  = (const float*)d_in[10];
    const float* lin2w  = (const float*)d_in[11];
    const float* lin2b  = (const float*)d_in[12];
    float* out = (float*)d_out;

    const int* src = ei;
    const int* dst = ei + EE;

    char* ws = (char*)d_ws;
    size_t off = 0;
    auto carve = [&](size_t bytes) {
        void* p = ws + off;
        off = (off + bytes + 255) & ~(size_t)255;
        return p;
    };
    // zero-initialized group first (single memset covers [0, zero_span))
    int*      deg      = (int*)carve((size_t)NN * 4);
    float*    pooled   = (float*)carve((size_t)GG * 64 * 4);
    int*      cnt      = (int*)carve((size_t)GG * 4);
    size_t zero_span = off;
    float*    dinv     = (float*)carve((size_t)(NN + 1) * 4);
    int*      rowptr   = (int*)carve((size_t)(NN + 1) * 4);
    int*      bsum     = (int*)carve((size_t)SCAN_NB * 4);
    ushort_t* rank     = (ushort_t*)carve((size_t)EE * 2);
    ushort_t* csr_src  = (ushort_t*)carve((size_t)(EE + 16) * 2); // +16 masked overrun
    ushort_t* bufT     = (ushort_t*)carve((size_t)(NN + 1) * 64 * 2);  // bf16, +1 zero row
    float*    bufA     = (float*)carve((size_t)NN * 64 * 4);

    hipMemsetAsync(deg, 0, zero_span, stream);

    // ---- CSR build (rank-based, atomic-free fill) ----
    k_deg  <<<(EE + NN + 255) / 256, 256, 0, stream>>>(dst, batch, deg, rank, cnt);
    k_scan1<<<SCAN_NB, 1024, 0, stream>>>(deg, rowptr, bsum, dinv);
    k_scan2<<<1, 64, 0, stream>>>(bsum);
    k_fill <<<(EE + 255) / 256, 256, 0, stream>>>(src, dst, rank, rowptr, bsum, csr_src);

    const int xgrid = (NN + 1 + 31) / 32;        // includes zero row NN
    const int ggrid = (NN * 64) / 256;           // one 64-lane wave per node

    // layer 0: x -> bufA
    k_xform<false><<<xgrid, 256, 0, stream>>>(x, W0, dinv, bufT);
    k_gather<false><<<ggrid, 256, 0, stream>>>(bufT, dinv, rowptr, bsum, csr_src,
                                               b0, batch, bufA);
    // layer 1
    k_xform<true><<<xgrid, 256, 0, stream>>>(bufA, W1, dinv, bufT);
    k_gather<false><<<ggrid, 256, 0, stream>>>(bufT, dinv, rowptr, bsum, csr_src,
                                               b1, batch, bufA);
    // layer 2: relu + mean-pool fused into gather
    k_xform<true><<<xgrid, 256, 0, stream>>>(bufA, W2, dinv, bufT);
    k_gather<true><<<ggrid, 256, 0, stream>>>(bufT, dinv, rowptr, bsum, csr_src,
                                              b2, batch, pooled);

    k_head<<<GG, 64, 0, stream>>>(pooled, cnt, lin1w, lin1b, lin2w, lin2b, out);
}

// Round 16
// 319.839 us; speedup vs baseline: 1.4682x; 1.0132x over previous
//
#include <hip/hip_runtime.h>
#include <math.h>

#define NN 50000
#define EE 800000
#define HH 64
#define GG 512
#define SCAN_NB ((NN + 1023) / 1024)       // 49 blocks (covers NN+1 entries)

typedef unsigned short ushort_t;
typedef unsigned int uint_t;

__device__ __forceinline__ ushort_t f32_to_bf16(float f) {
    uint_t u = __float_as_uint(f);
    uint_t bias = 0x7FFFu + ((u >> 16) & 1u);    // round-to-nearest-even
    return (ushort_t)((u + bias) >> 16);
}
__device__ __forceinline__ float bf16_to_f32(ushort_t h) {
    return __uint_as_float(((uint_t)h) << 16);
}

// ---------------- degree + per-edge rank (old value of the atomic) ----------------
// Identical to the R12-measured version: int rank, edges only.

__global__ void k_deg(const int* __restrict__ dst, int* __restrict__ deg,
                      int* __restrict__ rank) {
    int e = blockIdx.x * blockDim.x + threadIdx.x;
    if (e < EE) rank[e] = atomicAdd(&deg[dst[e]], 1);
}

// ---------------- scan: deg -> block-local rowptr + block sums (+ dinv) ----------------

__global__ void __launch_bounds__(1024) k_scan1(const int* __restrict__ deg,
                                                int* __restrict__ rowptr,
                                                int* __restrict__ bsum,
                                                float* __restrict__ dinv) {
    int tid = threadIdx.x;
    int lane = tid & 63, w = tid >> 6;
    int i = blockIdx.x * 1024 + tid;
    int v = (i < NN) ? deg[i] : 0;
    if (i < NN)       dinv[i] = 1.0f / sqrtf((float)(v + 1));   // +1 self-loop
    else if (i == NN) dinv[i] = 0.0f;                           // zero row
    int x = v;                                                  // inclusive wave scan
#pragma unroll
    for (int off = 1; off < 64; off <<= 1) {
        int y = __shfl_up(x, off);
        if (lane >= off) x += y;
    }
    __shared__ int ws[16];
    if (lane == 63) ws[w] = x;
    __syncthreads();
    if (tid < 16) {
        int y = ws[tid];
        int z = y;
#pragma unroll
        for (int off = 1; off < 16; off <<= 1) {
            int t2 = __shfl_up(z, off);
            if (tid >= off) z += t2;
        }
        ws[tid] = z - y;                          // exclusive wave offsets
    }
    __syncthreads();
    int excl = x - v + ws[w];
    if (i <= NN) rowptr[i] = excl;                // block-local exclusive prefix
    if (tid == 1023) bsum[blockIdx.x] = excl + v; // block total
}

__global__ void __launch_bounds__(64) k_scan2(int* __restrict__ bsum) {
    int lane = threadIdx.x;
    int v = (lane < SCAN_NB) ? bsum[lane] : 0;
    int x = v;
#pragma unroll
    for (int off = 1; off < 64; off <<= 1) {
        int y = __shfl_up(x, off);
        if (lane >= off) x += y;
    }
    if (lane < SCAN_NB) bsum[lane] = x - v;       // exclusive block offsets
}

// ---------------- CSR fill: atomic-free u16 edge scatter + per-graph counts ----------------

__global__ void k_fill(const int* __restrict__ src, const int* __restrict__ dst,
                       const int* __restrict__ rank,
                       const int* __restrict__ rowptr, const int* __restrict__ bsum,
                       const int* __restrict__ batch,
                       ushort_t* __restrict__ csr_src, int* __restrict__ cnt) {
    int tid = blockIdx.x * blockDim.x + threadIdx.x;
    if (tid < EE) {
        int d = dst[tid];
        csr_src[rowptr[d] + bsum[d >> 10] + rank[tid]] = (ushort_t)src[tid];
    } else if (tid < EE + NN) {
        atomicAdd(&cnt[batch[tid - EE]], 1);
    }
}

// ---------------- dense transform: t' = bf16((act(x) @ W) * dinv[row]); row NN zeroed ------

template<bool RELU>
__global__ void __launch_bounds__(256) k_xform(const float* __restrict__ x,
                                               const float* __restrict__ W,
                                               const float* __restrict__ dinv,
                                               ushort_t* __restrict__ t) {
    __shared__ float sW[64 * 64];   // 16 KB
    __shared__ float sX[32 * 65];   // padded
    int tid = threadIdx.x;
    for (int k = tid; k < 64 * 64; k += 256) sW[k] = W[k];
    int row0 = blockIdx.x * 32;
    for (int v = tid; v < 32 * 16; v += 256) {
        int r  = v >> 4;
        int k4 = (v & 15) * 4;
        int row = row0 + r;
        float4 val = make_float4(0.f, 0.f, 0.f, 0.f);
        if (row < NN) val = *(const float4*)(x + (size_t)row * 64 + k4);
        if (RELU) {
            val.x = fmaxf(val.x, 0.f); val.y = fmaxf(val.y, 0.f);
            val.z = fmaxf(val.z, 0.f); val.w = fmaxf(val.w, 0.f);
        }
        sX[r * 65 + k4 + 0] = val.x;
        sX[r * 65 + k4 + 1] = val.y;
        sX[r * 65 + k4 + 2] = val.z;
        sX[r * 65 + k4 + 3] = val.w;
    }
    __syncthreads();
    int r  = tid >> 3;        // 0..31
    int c0 = (tid & 7) * 8;   // 0,8,...,56
    float acc[8] = {0.f, 0.f, 0.f, 0.f, 0.f, 0.f, 0.f, 0.f};
    for (int k = 0; k < 64; ++k) {
        float xv = sX[r * 65 + k];
#pragma unroll
        for (int j = 0; j < 8; ++j) acc[j] = fmaf(xv, sW[k * 64 + c0 + j], acc[j]);
    }
    int row = row0 + r;
    if (row <= NN) {          // row NN: acc==0 -> writes zero row
        float dv = dinv[row];
        uint_t pk[4];
#pragma unroll
        for (int j = 0; j < 4; ++j) {
            ushort_t lo = f32_to_bf16(acc[2 * j] * dv);
            ushort_t hi = f32_to_bf16(acc[2 * j + 1] * dv);
            pk[j] = (uint_t)lo | ((uint_t)hi << 16);
        }
        uint4* o = (uint4*)(t + (size_t)row * 64 + c0);   // 16 B per lane
        *o = make_uint4(pk[0], pk[1], pk[2], pk[3]);
    }
}

// ---------------- CSR gather: one wave per node, 16-deep batches, bf16 rows, u16 idx -------
// out[i] = dinv[i] * (t'[i] + sum_{s in N(i)} t'[s]) + b

template<bool POOL>
__global__ void __launch_bounds__(256) k_gather(const ushort_t* __restrict__ t,
                                                const float* __restrict__ dinv,
                                                const int* __restrict__ rowptr,
                                                const int* __restrict__ bsum,
                                                const ushort_t* __restrict__ csr_src,
                                                const float* __restrict__ b,
                                                const int* __restrict__ batch,
                                                float* __restrict__ out) {
    int i = __builtin_amdgcn_readfirstlane((blockIdx.x * blockDim.x + threadIdx.x) >> 6);
    int c = threadIdx.x & 63;
    if (i >= NN) return;
    int e   = __builtin_amdgcn_readfirstlane(rowptr[i]     + bsum[i >> 10]);
    int end = __builtin_amdgcn_readfirstlane(rowptr[i + 1] + bsum[(i + 1) >> 10]);
    float acc = bf16_to_f32(t[(size_t)i * 64 + c]);   // self-loop (t' already *dinv[i])
    float a0 = 0.f, a1 = 0.f, a2 = 0.f, a3 = 0.f;
    for (; e < end; e += 16) {                    // 16 outstanding row-gathers
        int s[16];
#pragma unroll
        for (int j = 0; j < 16; ++j) {
            int sj = (int)csr_src[e + j];         // uniform addr -> scalar-load, broadcast
            s[j] = (e + j < end) ? sj : NN;       // uniform select; NN = zero row
        }
        ushort_t v[16];
#pragma unroll
        for (int j = 0; j < 16; ++j) v[j] = t[(size_t)s[j] * 64 + c];
#pragma unroll
        for (int j = 0; j < 16; ++j) {
            float f = bf16_to_f32(v[j]);
            if ((j & 3) == 0)      a0 += f;
            else if ((j & 3) == 1) a1 += f;
            else if ((j & 3) == 2) a2 += f;
            else                   a3 += f;
        }
    }
    acc += (a0 + a1) + (a2 + a3);
    float r = fmaf(acc, dinv[i], b[c]);
    if (POOL) {
        atomicAdd(&out[(size_t)batch[i] * 64 + c], fmaxf(r, 0.0f));
    } else {
        out[(size_t)i * 64 + c] = r;
    }
}

// ---------------- head: per-graph MLP, one wave per graph ----------------

__global__ void __launch_bounds__(64) k_head(const float* __restrict__ pooled,
                                             const int* __restrict__ cnt,
                                             const float* __restrict__ w1,
                                             const float* __restrict__ b1,
                                             const float* __restrict__ w2,
                                             const float* __restrict__ b2,
                                             float* __restrict__ out) {
    int g = blockIdx.x;
    int c = threadIdx.x;
    __shared__ float sp[64];
    float cf = fmaxf((float)cnt[g], 1.0f);
    sp[c] = pooled[(size_t)g * 64 + c] / cf;
    __syncthreads();
    float acc = b1[c];
    for (int k = 0; k < 64; ++k) acc = fmaf(sp[k], w1[k * 64 + c], acc);
    float h1 = fmaxf(acc, 0.0f);
    float p = h1 * w2[c];
#pragma unroll
    for (int off = 32; off > 0; off >>= 1) p += __shfl_down(p, off);
    if (c == 0) out[g] = p + b2[0];
}

// ---------------- launch ----------------

extern "C" void kernel_launch(void* const* d_in, const int* in_sizes, int n_in,
                              void* d_out, int out_size, void* d_ws, size_t ws_size,
                              hipStream_t stream) {
    const float* x      = (const float*)d_in[0];
    const int*   ei     = (const int*)d_in[1];
    const int*   batch  = (const int*)d_in[2];
    const float* W0     = (const float*)d_in[3];
    const float* b0     = (const float*)d_in[4];
    const float* W1     = (const float*)d_in[5];
    const float* b1     = (const float*)d_in[6];
    const float* W2     = (const float*)d_in[7];
    const float* b2     = (const float*)d_in[8];
    const float* lin1w  = (const float*)d_in[9];
    const float* lin1b  = (const float*)d_in[10];
    const float* lin2w  = (const float*)d_in[11];
    const float* lin2b  = (const float*)d_in[12];
    float* out = (float*)d_out;

    const int* src = ei;
    const int* dst = ei + EE;

    char* ws = (char*)d_ws;
    size_t off = 0;
    auto carve = [&](size_t bytes) {
        void* p = ws + off;
        off = (off + bytes + 255) & ~(size_t)255;
        return p;
    };
    // zero-initialized group first (single memset covers [0, zero_span))
    int*      deg      = (int*)carve((size_t)NN * 4);
    float*    pooled   = (float*)carve((size_t)GG * 64 * 4);
    int*      cnt      = (int*)carve((size_t)GG * 4);
    size_t zero_span = off;
    float*    dinv     = (float*)carve((size_t)(NN + 1) * 4);
    int*      rowptr   = (int*)carve((size_t)(NN + 1) * 4);
    int*      bsum     = (int*)carve((size_t)SCAN_NB * 4);
    int*      rank     = (int*)carve((size_t)EE * 4);
    ushort_t* csr_src  = (ushort_t*)carve((size_t)(EE + 16) * 2); // +16 masked overrun
    ushort_t* bufT     = (ushort_t*)carve((size_t)(NN + 1) * 64 * 2);  // bf16, +1 zero row
    float*    bufA     = (float*)carve((size_t)NN * 64 * 4);

    hipMemsetAsync(deg, 0, zero_span, stream);

    // ---- CSR build (rank-based, atomic-free u16 fill) ----
    k_deg  <<<(EE + 255) / 256, 256, 0, stream>>>(dst, deg, rank);
    k_scan1<<<SCAN_NB, 1024, 0, stream>>>(deg, rowptr, bsum, dinv);
    k_scan2<<<1, 64, 0, stream>>>(bsum);
    k_fill <<<(EE + NN + 255) / 256, 256, 0, stream>>>(src, dst, rank, rowptr,
                                                       bsum, batch, csr_src, cnt);

    const int xgrid = (NN + 1 + 31) / 32;        // includes zero row NN
    const int ggrid = (NN * 64) / 256;           // one 64-lane wave per node

    // layer 0: x -> bufA
    k_xform<false><<<xgrid, 256, 0, stream>>>(x, W0, dinv, bufT);
    k_gather<false><<<ggrid, 256, 0, stream>>>(bufT, dinv, rowptr, bsum, csr_src,
                                               b0, batch, bufA);
    // layer 1
    k_xform<true><<<xgrid, 256, 0, stream>>>(bufA, W1, dinv, bufT);
    k_gather<false><<<ggrid, 256, 0, stream>>>(bufT, dinv, rowptr, bsum, csr_src,
                                               b1, batch, bufA);
    // layer 2: relu + mean-pool fused into gather
    k_xform<true><<<xgrid, 256, 0, stream>>>(bufA, W2, dinv, bufT);
    k_gather<true><<<ggrid, 256, 0, stream>>>(bufT, dinv, rowptr, bsum, csr_src,
                                              b2, batch, pooled);

    k_head<<<GG, 64, 0, stream>>>(pooled, cnt, lin1w, lin1b, lin2w, lin2b, out);
}